// Round 1
// baseline (272.583 us; speedup 1.0000x reference)
//
#include <hip/hip_runtime.h>

// Problem constants (fixed by setup_inputs)
#define B_SZ   8192
#define CH     5120          // C*H = 20*256
#define CH4    1280          // CH / 4 (float4 columns per row)
#define K_LAB  10
#define EPS    1e-8f
#define FLTMAX 3.402823466e38f

// Pass-1 tiling: 128 row-chunks x 4 col-chunks = 512 blocks (2 per CU)
#define RC_N   128           // row chunks
#define ROWS   64            // rows per chunk (RC_N*ROWS == B_SZ)
#define CC_N   4             // col chunks
#define CCW    320           // float4 columns per col chunk (CC_N*CCW == CH4)
#define NT1    320           // pass-1 threads (5 waves; 1 float4 col/thread)

// Pass-2: 10 labels x 20 col-groups of 64 float4 columns
#define CG_N   20
#define NT2    64
#define RCSTRIDE (K_LAB * CC_N * CCW)   // 12800 float4 per row-chunk in P_sum

// loss = sum_{k: n_k>0} (SSQ_k - ||S_k||^2/n_k + n_k*CH*eps^2) / (n_k*CH)
// (2*eps cross-term cancels exactly: sum_{b in k}(z_b - mu_k) == 0)

__device__ __forceinline__ float4 sanitize(float4 v) {
    v.x = (v.x == v.x) ? fminf(fmaxf(v.x, -FLTMAX), FLTMAX) : 0.f;
    v.y = (v.y == v.y) ? fminf(fmaxf(v.y, -FLTMAX), FLTMAX) : 0.f;
    v.z = (v.z == v.z) ? fminf(fmaxf(v.z, -FLTMAX), FLTMAX) : 0.f;
    v.w = (v.w == v.w) ? fminf(fmaxf(v.w, -FLTMAX), FLTMAX) : 0.f;
    return v;
}

// ---------------------------------------------------------------------------
// Pass 1: stream z contiguously; predicated per-label accumulation in regs.
// No index lists, no serial setup, no atomics on the hot path.
__global__ __launch_bounds__(NT1) void codi_pass1(
    const float4* __restrict__ z4, const int* __restrict__ labels,
    float4* __restrict__ P_sum, float* __restrict__ P_ssq,
    int* __restrict__ P_cnt, int* __restrict__ done)
{
    const int tid = threadIdx.x;
    const int rc  = blockIdx.x >> 2;     // row-chunk
    const int cc  = blockIdx.x & 3;      // col-chunk

    __shared__ int   lab_s[ROWS];
    __shared__ float wssq[5][K_LAB];

    if (blockIdx.x == 0 && tid == 0) *done = 0;   // re-init ticket (poisoned ws)

    if (tid < ROWS) lab_s[tid] = labels[rc * ROWS + tid];
    __syncthreads();

    float4 sum[K_LAB];
    float  ssq[K_LAB];
    #pragma unroll
    for (int k = 0; k < K_LAB; ++k) {
        sum[k] = make_float4(0.f, 0.f, 0.f, 0.f);
        ssq[k] = 0.f;
    }

    // thread owns one float4 column; rows are contiguous -> pure streaming
    const float4* zp = z4 + (size_t)rc * ROWS * CH4 + cc * CCW + tid;

    for (int r = 0; r < ROWS; r += 8) {
        float4 v[8];
        #pragma unroll
        for (int u = 0; u < 8; ++u) v[u] = zp[(size_t)(r + u) * CH4];

        #pragma unroll
        for (int u = 0; u < 8; ++u) {
            // label is uniform across the block for this row -> scalarize
            const int lab = __builtin_amdgcn_readfirstlane(lab_s[r + u]);
            float4 t = sanitize(v[u]);
            float  q = fmaf(t.x, t.x, fmaf(t.y, t.y, fmaf(t.z, t.z, t.w * t.w)));
            #pragma unroll
            for (int k = 0; k < K_LAB; ++k) {
                const float w = (lab == k) ? 1.f : 0.f;   // scalar operand
                sum[k].x = fmaf(t.x, w, sum[k].x);
                sum[k].y = fmaf(t.y, w, sum[k].y);
                sum[k].z = fmaf(t.z, w, sum[k].z);
                sum[k].w = fmaf(t.w, w, sum[k].w);
                ssq[k]   = fmaf(q,   w, ssq[k]);
            }
        }
    }

    // per-label partial row-sums: 10 x 5 KB coalesced float4 stores
    #pragma unroll
    for (int k = 0; k < K_LAB; ++k)
        P_sum[(((size_t)rc * K_LAB + k) * CC_N + cc) * CCW + tid] = sum[k];

    // block-reduce ssq[k] -> P_ssq[(rc*4+cc)*10 + k]
    const int lane = tid & 63, wid = tid >> 6;
    #pragma unroll
    for (int k = 0; k < K_LAB; ++k) {
        float s = ssq[k];
        #pragma unroll
        for (int o = 32; o > 0; o >>= 1) s += __shfl_down(s, o, 64);
        if (lane == 0) wssq[wid][k] = s;
    }
    __syncthreads();
    if (tid < K_LAB) {
        float s = wssq[0][tid] + wssq[1][tid] + wssq[2][tid]
                + wssq[3][tid] + wssq[4][tid];
        P_ssq[(rc * CC_N + cc) * K_LAB + tid] = s;
    }

    // per-chunk label counts (one writer: cc==0, wave 0, 10 ballots)
    if (cc == 0 && tid < 64) {
        const int lab = lab_s[tid];
        #pragma unroll
        for (int k = 0; k < K_LAB; ++k) {
            unsigned long long m = __ballot(lab == k);
            if (tid == k) P_cnt[rc * K_LAB + k] = __popcll(m);
        }
    }
}

// ---------------------------------------------------------------------------
// Pass 2: fold 128 row-chunk partials per (label, column) -> ||S_k||^2;
// cg==0 blocks fold SSQ_k and n_k; last-ticket block finalizes the loss.
__global__ __launch_bounds__(NT2) void codi_pass2(
    const float4* __restrict__ P_sum, const float* __restrict__ P_ssq,
    const int* __restrict__ P_cnt, float* __restrict__ pn,
    float* __restrict__ ssqk, float* __restrict__ cntk,
    int* __restrict__ done, float* __restrict__ out)
{
    const int tid = threadIdx.x;
    const int k   = blockIdx.x / CG_N;
    const int cg  = blockIdx.x % CG_N;
    const int c   = cg * NT2 + tid;      // 0..1279 (float4 column)
    const int cc  = c / CCW;
    const int co  = c % CCW;

    const float4* p = P_sum + ((size_t)k * CC_N + cc) * CCW + co;
    float4 s = make_float4(0.f, 0.f, 0.f, 0.f);
    #pragma unroll 16
    for (int rc = 0; rc < RC_N; ++rc) {   // L3-hot, 16 loads in flight
        float4 v = p[(size_t)rc * RCSTRIDE];
        s.x += v.x; s.y += v.y; s.z += v.z; s.w += v.w;
    }
    float q = fmaf(s.x, s.x, fmaf(s.y, s.y, fmaf(s.z, s.z, s.w * s.w)));
    #pragma unroll
    for (int o = 32; o > 0; o >>= 1) q += __shfl_down(q, o, 64);
    if (tid == 0) pn[k * CG_N + cg] = q;

    if (cg == 0) {   // fold SSQ_k and n_k (K1-written data: plain loads OK)
        float s2 = 0.f;
        for (int i = tid; i < RC_N * CC_N; i += NT2) s2 += P_ssq[i * K_LAB + k];
        #pragma unroll
        for (int o = 32; o > 0; o >>= 1) s2 += __shfl_down(s2, o, 64);
        int n = 0;
        for (int i = tid; i < RC_N; i += NT2) n += P_cnt[i * K_LAB + k];
        #pragma unroll
        for (int o = 32; o > 0; o >>= 1) n += __shfl_down(n, o, 64);
        if (tid == 0) { ssqk[k] = s2; cntk[k] = (float)n; }
    }

    __threadfence();
    __shared__ int ticket;
    if (tid == 0) ticket = atomicAdd(done, 1);
    __syncthreads();

    if (ticket == K_LAB * CG_N - 1) {    // last block: all writes visible
        float acc = 0.f;
        for (int k2 = 0; k2 < K_LAB; ++k2) {
            float np = 0.f;              // coherent reads of K2-written data
            if (tid < CG_N) np = atomicAdd(&pn[k2 * CG_N + tid], 0.f);
            #pragma unroll
            for (int o = 32; o > 0; o >>= 1) np += __shfl_down(np, o, 64);
            if (tid == 0) {
                float nn = atomicAdd(&cntk[k2], 0.f);
                float s2 = atomicAdd(&ssqk[k2], 0.f);
                if (nn > 0.f) {
                    float sse = s2 - np / nn + nn * (float)CH * (EPS * EPS);
                    float mse = sse / (nn * (float)CH);
                    if (mse == mse) acc += mse;    // nan_to_num(mse_k)
                }
            }
        }
        if (tid == 0) out[0] = acc;
    }
}

// ---------------------------------------------------------------------------
extern "C" void kernel_launch(void* const* d_in, const int* in_sizes, int n_in,
                              void* d_out, int out_size, void* d_ws, size_t ws_size,
                              hipStream_t stream) {
    const float4* z4     = (const float4*)d_in[0];
    const int*    labels = (const int*)d_in[1];

    // ws layout (float units):
    //   [0] done (int) | [16..216) pn[200] | [224..234) ssqk | [240..250) cntk
    //   [256..1536) P_cnt[1280] (int) | [1536..6656) P_ssq[5120]
    //   [6720..) P_sum: 128*10*4*320 float4  (byte off 26880, 16B-aligned)
    float*  hdr   = (float*)d_ws;
    int*    done  = (int*)hdr;
    float*  pn    = hdr + 16;
    float*  ssqk  = hdr + 224;
    float*  cntk  = hdr + 240;
    int*    P_cnt = (int*)(hdr + 256);
    float*  P_ssq = hdr + 1536;
    float4* P_sum = (float4*)(hdr + 6720);

    codi_pass1<<<RC_N * CC_N, NT1, 0, stream>>>(z4, labels, P_sum, P_ssq, P_cnt, done);
    codi_pass2<<<K_LAB * CG_N, NT2, 0, stream>>>(P_sum, P_ssq, P_cnt, pn, ssqk,
                                                 cntk, done, (float*)d_out);
}